// Round 6
// baseline (106.414 us; speedup 1.0000x reference)
//
#include <hip/hip_runtime.h>
#include <math.h>

#define GRID_N 5
#define LOG2E 1.4426950408889634f
#define EXP2F __builtin_amdgcn_exp2f
#define BATCH 2048

// Build per-(i,o) bin tables:
//   K = -s*log2e
//   A[k] = sum_{g_idx < k} w_g * 2^{-K*g},  B[k] = sum_{g_idx >= k} w_g * 2^{+K*g}
// T[i][k][o][2] = {A,B} (k=0..5);  Kt[i][o] = K
__device__ __forceinline__ void prep_one(const float* __restrict__ w,
                                         const float* __restrict__ s,
                                         float* __restrict__ T, float* __restrict__ Kt,
                                         int O, int I, int idx) {
    int o = idx / I, i = idx % I;               // w,s are [O][I(][G)]
    float K = -s[idx] * LOG2E;
    const float gv[5] = {-1.f, -0.5f, 0.f, 0.5f, 1.f};
    float A[6], B[6];
    A[0] = 0.f; B[5] = 0.f;
#pragma unroll
    for (int g = 0; g < 5; g++)
        A[g + 1] = A[g] + w[idx * GRID_N + g] * EXP2F(-K * gv[g]);
#pragma unroll
    for (int g = 4; g >= 0; g--)
        B[g] = B[g + 1] + w[idx * GRID_N + g] * EXP2F(K * gv[g]);
#pragma unroll
    for (int k = 0; k < 6; k++) {
        T[((i * 6 + k) * O + o) * 2 + 0] = A[k];
        T[((i * 6 + k) * O + o) * 2 + 1] = B[k];
    }
    Kt[i * O + o] = K;
}

__global__ __launch_bounds__(256) void prep_all(
    const float* __restrict__ w1, const float* __restrict__ s1, float* T1, float* K1,
    const float* __restrict__ w2, const float* __restrict__ s2, float* T2, float* K2,
    const float* __restrict__ w3, const float* __restrict__ s3, float* T3, float* K3) {
    int idx = blockIdx.x * 256 + threadIdx.x;
    if (idx < 32768)       prep_one(w1, s1, T1, K1, 256, 128, idx);
    else if (idx < 65536)  prep_one(w2, s2, T2, K2, 128, 256, idx - 32768);
    else if (idx < 73728)  prep_one(w3, s3, T3, K3,  64, 128, idx - 65536);
}

// out[b,o] (+)= sum_{i in my half} A[i,bin,o]*2^{K*xn} + B[i,bin,o]*2^{-K*xn}
// xn = tanh(x), x = raw input (XMODE 0) or relu(p0+p1) partial combine (XMODE 1).
// Wave = 64 o's (lane=o) x 1 b-row x (IN/ISPLIT) i's. Block's 4 waves share
// (oc, half), consecutive b -> T/K line L1 reuse.
// ISPLIT>1 -> write raw partial to outp[half][B][OUT]; else apply ACT.
template<int IN, int OUT, int ACT, int ISPLIT, int XMODE>
__global__ __launch_bounds__(256, 8) void kan_layer(
    const float* __restrict__ xin,   // XMODE0: [B][IN]; XMODE1: [2][B][IN] partials
    const char*  __restrict__ Tb,    // [IN][6][OUT][2] floats, as bytes
    const float* __restrict__ Kt,    // [IN][OUT]
    float* __restrict__ outp)        // [ISPLIT][B][OUT]
{
    constexpr int LEN = IN / ISPLIT;           // i's per wave
    constexpr int CH  = LEN / 64;
    constexpr unsigned ROWB = OUT * 8;

    const int lane = threadIdx.x & 63;
    const int wid  = (blockIdx.x << 2) | (threadIdx.x >> 6);
    const int oc   = wid / (BATCH * ISPLIT);
    const int rem  = wid % (BATCH * ISPLIT);
    const int half = rem / BATCH;
    const int b    = rem % BATCH;
    const int o    = (oc << 6) | lane;
    const int ibase = half * LEN;

    // per-lane tanh + full byte offset (i*6+bin)*ROWB  (lane l -> i = ibase+c*64+l)
    float    xv[CH];
    unsigned off[CH];
#pragma unroll
    for (int c = 0; c < CH; c++) {
        int   i = ibase + (c << 6) + lane;
        float v;
        if (XMODE == 0) {
            v = xin[b * IN + i];
        } else {
            v = fmaxf(xin[b * IN + i] + xin[(BATCH * IN) + b * IN + i], 0.f);
        }
        float ex = EXP2F(2.0f * LOG2E * v);
        float t  = 1.0f - 2.0f / (ex + 1.0f);  // tanh, NaN-safe
        xv[c] = t;
        int k = (int)((t + 1.0f) * 2.0f) + 1;  // #{g <= t}, t in [-1,1]
        k = k > 5 ? 5 : k;
        off[c] = (unsigned)(i * 6 + k) * ROWB;
    }

    float acc = 0.f;
    const unsigned o8 = (unsigned)o * 8u;
    const float*   Kp = Kt + o;

#pragma unroll
    for (int c = 0; c < CH; c++) {
        for (int lb = 0; lb < 8; lb++) {       // dynamic batch loop: 8 i's/batch
            float2 ab[8];
            float  Kv[8];
#pragma unroll
            for (int u = 0; u < 8; u++) {
                const int l = lb * 8 + u;      // wave-uniform lane index
                const int i = ibase + (c << 6) + l;
                Kv[u] = Kp[i * OUT];
                unsigned os = (unsigned)__builtin_amdgcn_readlane((int)off[c], l);
                ab[u] = *(const float2*)(Tb + (os + o8));
            }
#pragma unroll
            for (int u = 0; u < 8; u++) {
                const int l = lb * 8 + u;
                float xs = __int_as_float(__builtin_amdgcn_readlane(__float_as_int(xv[c]), l));
                float t  = Kv[u] * xs;
                acc += ab[u].x * EXP2F(t) + ab[u].y * EXP2F(-t);
            }
        }
    }

    if (ISPLIT == 1) {
        float z = acc;
        if (ACT == 0) z = fmaxf(z, 0.f);
        else          z = 1.0f / (1.0f + EXP2F(-LOG2E * z));
        outp[b * OUT + o] = z;
    } else {
        outp[(half * BATCH + b) * OUT + o] = acc;   // raw partial
    }
}

// out[e] = sigmoid(p0[e] + p1[e])
__global__ __launch_bounds__(256) void sigmoid_combine(
    const float* __restrict__ p, float* __restrict__ out, int n) {
    int e = blockIdx.x * 256 + threadIdx.x;
    if (e >= n) return;
    float z = p[e] + p[n + e];
    out[e] = 1.0f / (1.0f + EXP2F(-LOG2E * z));
}

extern "C" void kernel_launch(void* const* d_in, const int* in_sizes, int n_in,
                              void* d_out, int out_size, void* d_ws, size_t ws_size,
                              hipStream_t stream) {
    const float* x  = (const float*)d_in[0];
    const float* w1 = (const float*)d_in[1];
    const float* s1 = (const float*)d_in[2];
    const float* w2 = (const float*)d_in[3];
    const float* s2 = (const float*)d_in[4];
    const float* w3 = (const float*)d_in[5];
    const float* s3 = (const float*)d_in[6];
    float* out = (float*)d_out;

    float* ws  = (float*)d_ws;
    float* h1  = ws;                    // 2048*256            = 524288  (also aliased by part3 later)
    float* p2  = h1  + 524288;          // 2*2048*128          = 524288
    float* T1  = p2  + 524288;          // 128*6*256*2         = 393216
    float* K1  = T1  + 393216;          // 128*256             = 32768
    float* T2  = K1  + 32768;           // 256*6*128*2         = 393216
    float* K2  = T2  + 393216;          // 256*128             = 32768
    float* T3  = K2  + 32768;           // 128*6*64*2          = 98304
    float* K3  = T3  + 98304;           // 128*64              = 8192
    float* p3  = h1;                    // alias: h1 dead once L2 done (2*2048*64 = 262144 <= 524288)

    prep_all<<<288, 256, 0, stream>>>(w1, s1, T1, K1, w2, s2, T2, K2, w3, s3, T3, K3);

    // L1: 2048 bg x 4 oc = 8192 waves -> 2048 blocks (32 waves/CU)
    kan_layer<128, 256, 0, 1, 0><<<2048, 256, 0, stream>>>(x,  (const char*)T1, K1, h1);
    // L2: 2048 bg x 2 oc x 2 halves = 8192 waves -> 2048 blocks; raw partials
    kan_layer<256, 128, 0, 2, 0><<<2048, 256, 0, stream>>>(h1, (const char*)T2, K2, p2);
    // L3: 2048 bg x 1 oc x 2 halves = 4096 waves -> 1024 blocks; stages relu(p0+p1)
    kan_layer<128,  64, 1, 2, 1><<<1024, 256, 0, stream>>>(p2, (const char*)T3, K3, p3);
    // epilogue: sigmoid(p0+p1) -> out  (2048*64 = 131072 elems)
    sigmoid_combine<<<512, 256, 0, stream>>>(p3, out, 131072);
}